// Round 2
// baseline (457.698 us; speedup 1.0000x reference)
//
#include <hip/hip_runtime.h>
#include <hip/hip_bf16.h>

typedef __attribute__((ext_vector_type(8))) short short8;
typedef __attribute__((ext_vector_type(4))) float f32x4;

#define MFMA16(a, b, c) __builtin_amdgcn_mfma_f32_16x16x32_bf16((a), (b), (c), 0, 0, 0)

__device__ __forceinline__ unsigned short f2bf(float x) {
    union { float f; unsigned int u; } v; v.f = x;
    unsigned int u = v.u;
    return (unsigned short)((u + 0x7FFFu + ((u >> 16) & 1u)) >> 16);
}

__device__ __forceinline__ short8 ld8(const unsigned short* p) {
    return *reinterpret_cast<const short8*>(p);
}

// ---- K0: bbn fp32 -> bf16, row sums s[i] (fp32) ------------------------------
__global__ void k_prep_bbn(const float* __restrict__ bbn, unsigned short* __restrict__ bbn_h,
                           float* __restrict__ s) {
    int row = blockIdx.x * 4 + (threadIdx.x >> 6);
    int lane = threadIdx.x & 63;
    float x = bbn[row * 64 + lane];
    bbn_h[row * 64 + lane] = f2bf(x);
    float v = x;
    #pragma unroll
    for (int m = 1; m < 64; m <<= 1) v += __shfl_xor(v, m);
    if (lane == 0) s[row] = v;
}

// ---- K0b/K2: transpose (+optional rsqrt(d) row scale), fp32 -> bf16 ----------
// out[n][k] = in[k][n] * (dvec ? rsqrt(dvec[k]) : 1)
__global__ void k_transpose_scale(const float* __restrict__ in, unsigned short* __restrict__ out,
                                  const float* __restrict__ dvec, int K, int N) {
    __shared__ float tile[64][65];
    int tiles_k = K >> 6;
    int tk = blockIdx.x % tiles_k, tn = blockIdx.x / tiles_k;
    int k0 = tk * 64, n0 = tn * 64;
    int c = threadIdx.x & 63, rq = threadIdx.x >> 6;
    #pragma unroll
    for (int i = 0; i < 16; ++i) {
        int r = rq + 4 * i;
        float sc = dvec ? rsqrtf(dvec[k0 + r]) : 1.0f;
        tile[r][c] = in[(size_t)(k0 + r) * N + n0 + c] * sc;
    }
    __syncthreads();
    #pragma unroll
    for (int i = 0; i < 16; ++i) {
        int r = rq + 4 * i;
        out[(size_t)(n0 + r) * K + k0 + c] = f2bf(tile[c][r]);
    }
}

// ---- K1: degree d[i] = sum_j (1 - |2*G_ij - s_i - s_j|/64)^1.4 ---------------
__global__ __launch_bounds__(512) void k_degree(const unsigned short* __restrict__ bbn_h,
                                                const float* __restrict__ s,
                                                float* __restrict__ d) {
    int i0 = blockIdx.x * 32;
    int tid = threadIdx.x;
    int w = tid >> 6, l = tid & 63, g = l >> 4, c = l & 15;
    int mi = w & 1, jj = w >> 1;

    int arow = i0 + mi * 16 + c;
    short8 a0 = ld8(bbn_h + arow * 64 + g * 8);
    short8 a1 = ld8(bbn_h + arow * 64 + 32 + g * 8);
    float si[4];
    #pragma unroll
    for (int r = 0; r < 4; ++r) si[r] = s[i0 + mi * 16 + g * 4 + r];

    float acc[4] = {0.f, 0.f, 0.f, 0.f};
    for (int j0 = 0; j0 < 8192; j0 += 64) {
        int jrow = j0 + jj * 16 + c;
        short8 b0 = ld8(bbn_h + jrow * 64 + g * 8);
        short8 b1 = ld8(bbn_h + jrow * 64 + 32 + g * 8);
        float sj = s[jrow];
        f32x4 gf = {0.f, 0.f, 0.f, 0.f};
        gf = MFMA16(a0, b0, gf);
        gf = MFMA16(a1, b1, gf);
        #pragma unroll
        for (int r = 0; r < 4; ++r) {
            float t = fmaf(2.f, gf[r], -(si[r] + sj));
            float x = fmaf(fabsf(t), -0.015625f, 1.f);
            x = fmaxf(x, 0.f);
            acc[r] += exp2f(1.4f * log2f(x));
        }
    }

    __shared__ float part[8][16];
    #pragma unroll
    for (int r = 0; r < 4; ++r) {
        float v = acc[r];
        v += __shfl_xor(v, 1); v += __shfl_xor(v, 2);
        v += __shfl_xor(v, 4); v += __shfl_xor(v, 8);
        if (c == 0) part[w][g * 4 + r] = v;
    }
    __syncthreads();
    if (tid < 32) {
        int row = tid & 15, m2 = tid >> 4;
        float v = part[m2][row] + part[m2 + 2][row] + part[m2 + 4][row] + part[m2 + 6][row];
        d[i0 + m2 * 16 + row] = v;
    }
}

// ---- K3: fused h = D^-1/2 A D^-1/2 cbn, adjacency generated on the fly -------
// BM=64, BN=256, BK=64; 512 threads (8 waves, 2x4); h bf16 [8192][512]
__global__ __launch_bounds__(512) void k_spectral(const unsigned short* __restrict__ bbn_h,
                                                  const float* __restrict__ s,
                                                  const float* __restrict__ d,
                                                  const unsigned short* __restrict__ cbn_sT,
                                                  unsigned short* __restrict__ h) {
    int bx = blockIdx.x;
    // XCD-aware: XCDs 0-3 -> col tile 0, XCDs 4-7 -> col tile 1 (4MB B slice per XCD L2)
    int xcd = bx & 7, hi = bx >> 3;
    int i0 = (hi * 4 + (xcd & 3)) * 64;
    int n0 = (xcd >> 2) * 256;

    int tid = threadIdx.x;
    int w = tid >> 6, l = tid & 63, g = l >> 4, c = l & 15;
    int wm = w >> 2, wn = w & 3;     // wave tile: rows wm*32, cols wn*64
    int gmi = w & 3, gjp = (w >> 2) * 2;  // gen: i-subtile gmi, j-subtiles gjp,gjp+1

    short8 ga0 = ld8(bbn_h + (i0 + gmi * 16 + c) * 64 + g * 8);
    short8 ga1 = ld8(bbn_h + (i0 + gmi * 16 + c) * 64 + 32 + g * 8);
    float si[4];
    #pragma unroll
    for (int r = 0; r < 4; ++r) si[r] = s[i0 + gmi * 16 + g * 4 + r];

    __shared__ unsigned char Alds[64 * 128];  // 64 rows x 64 bf16, XOR-swizzled

    f32x4 acc[2][4] = {};

    for (int j0 = 0; j0 < 8192; j0 += 64) {
        // prefetch B fragments (independent of LDS) to hide L2 latency under gen
        short8 bfr[2][4];
        #pragma unroll
        for (int kk = 0; kk < 2; ++kk)
            #pragma unroll
            for (int nn = 0; nn < 4; ++nn)
                bfr[kk][nn] = ld8(cbn_sT + (n0 + wn * 64 + nn * 16 + c) * 8192 + j0 + kk * 32 + g * 8);

        // ---- gen phase: A-tile [64 x 64] bf16 into swizzled LDS ----
        #pragma unroll
        for (int p = 0; p < 2; ++p) {
            int jj = gjp + p;
            int jrow = j0 + jj * 16 + c;
            short8 b0 = ld8(bbn_h + jrow * 64 + g * 8);
            short8 b1 = ld8(bbn_h + jrow * 64 + 32 + g * 8);
            float sj = s[jrow];
            f32x4 gf = {0.f, 0.f, 0.f, 0.f};
            gf = MFMA16(ga0, b0, gf);
            gf = MFMA16(ga1, b1, gf);
            #pragma unroll
            for (int r = 0; r < 4; ++r) {
                float t = fmaf(2.f, gf[r], -(si[r] + sj));
                float x = fmaf(fabsf(t), -0.015625f, 1.f);
                x = fmaxf(x, 0.f);
                float a = exp2f(1.4f * log2f(x));
                int row = gmi * 16 + g * 4 + r;
                int bo = (row * 128 + (jj * 16 + c) * 2) ^ ((row & 7) << 4);
                *(unsigned short*)(Alds + bo) = f2bf(a);
            }
        }
        __syncthreads();

        // ---- main phase ----
        short8 af[2][2];
        #pragma unroll
        for (int mi = 0; mi < 2; ++mi)
            #pragma unroll
            for (int kk = 0; kk < 2; ++kk) {
                int row = wm * 32 + mi * 16 + c;
                int bo = (row * 128 + kk * 64 + g * 16) ^ ((row & 7) << 4);
                af[mi][kk] = *(const short8*)(Alds + bo);
            }
        #pragma unroll
        for (int kk = 0; kk < 2; ++kk)
            #pragma unroll
            for (int nn = 0; nn < 4; ++nn) {
                acc[0][nn] = MFMA16(af[0][kk], bfr[kk][nn], acc[0][nn]);
                acc[1][nn] = MFMA16(af[1][kk], bfr[kk][nn], acc[1][nn]);
            }
        __syncthreads();
    }

    // epilogue: scale by dinv_i, store bf16 h
    #pragma unroll
    for (int mi = 0; mi < 2; ++mi) {
        #pragma unroll
        for (int r = 0; r < 4; ++r) {
            int row = i0 + wm * 32 + mi * 16 + g * 4 + r;
            float dinv = rsqrtf(d[row]);
            #pragma unroll
            for (int nn = 0; nn < 4; ++nn)
                h[row * 512 + n0 + wn * 64 + nn * 16 + c] = f2bf(acc[mi][nn][r] * dinv);
        }
    }
}

// ---- K4: out = sigmoid(h @ W + b), fp32 out ----------------------------------
__global__ __launch_bounds__(512) void k_out(const unsigned short* __restrict__ h,
                                             const unsigned short* __restrict__ Wt,
                                             const float* __restrict__ b,
                                             float* __restrict__ out) {
    int bx = blockIdx.x;
    int i0 = (bx & 127) * 64, n0 = (bx >> 7) * 256;
    int tid = threadIdx.x;
    int w = tid >> 6, l = tid & 63, g = l >> 4, c = l & 15;
    int wm = w >> 2, wn = w & 3;

    float bb[4];
    #pragma unroll
    for (int nn = 0; nn < 4; ++nn) bb[nn] = b[n0 + wn * 64 + nn * 16 + c];

    f32x4 acc[2][4] = {};
    for (int k0 = 0; k0 < 512; k0 += 64) {
        short8 af[2][2];
        #pragma unroll
        for (int mi = 0; mi < 2; ++mi)
            #pragma unroll
            for (int kk = 0; kk < 2; ++kk)
                af[mi][kk] = ld8(h + (i0 + wm * 32 + mi * 16 + c) * 512 + k0 + kk * 32 + g * 8);
        #pragma unroll
        for (int kk = 0; kk < 2; ++kk)
            #pragma unroll
            for (int nn = 0; nn < 4; ++nn) {
                short8 bf = ld8(Wt + (n0 + wn * 64 + nn * 16 + c) * 512 + k0 + kk * 32 + g * 8);
                acc[0][nn] = MFMA16(af[0][kk], bf, acc[0][nn]);
                acc[1][nn] = MFMA16(af[1][kk], bf, acc[1][nn]);
            }
    }
    #pragma unroll
    for (int mi = 0; mi < 2; ++mi)
        #pragma unroll
        for (int r = 0; r < 4; ++r) {
            int row = i0 + wm * 32 + mi * 16 + g * 4 + r;
            #pragma unroll
            for (int nn = 0; nn < 4; ++nn) {
                float z = acc[mi][nn][r] + bb[nn];
                out[row * 512 + n0 + wn * 64 + nn * 16 + c] = 1.f / (1.f + exp2f(-1.44269504f * z));
            }
        }
}

extern "C" void kernel_launch(void* const* d_in, const int* in_sizes, int n_in,
                              void* d_out, int out_size, void* d_ws, size_t ws_size,
                              hipStream_t stream) {
    const float* bbn = (const float*)d_in[0];   // [8192, 64]
    const float* cbn = (const float*)d_in[1];   // [8192, 512]
    const float* W   = (const float*)d_in[2];   // [512, 512]
    const float* b   = (const float*)d_in[3];   // [512]
    float* out = (float*)d_out;                 // [8192, 512] fp32

    char* ws = (char*)d_ws;
    unsigned short* bbn_h  = (unsigned short*)(ws);                    // 1 MB
    float*          s      = (float*)(ws + (1u << 20));                // 32 KB
    float*          dd     = (float*)(ws + (1u << 20) + (1u << 15));   // 32 KB
    unsigned short* Wt     = (unsigned short*)(ws + (1u << 20) + (2u << 15));           // 512 KB
    unsigned short* cbn_sT = (unsigned short*)(ws + (1u << 20) + (2u << 15) + (1u << 19));        // 8 MB
    unsigned short* hbuf   = (unsigned short*)(ws + (1u << 20) + (2u << 15) + (1u << 19) + (1u << 23)); // 8 MB

    k_prep_bbn<<<2048, 256, 0, stream>>>(bbn, bbn_h, s);
    k_transpose_scale<<<64, 256, 0, stream>>>(W, Wt, nullptr, 512, 512);
    k_degree<<<256, 512, 0, stream>>>(bbn_h, s, dd);
    k_transpose_scale<<<1024, 256, 0, stream>>>(cbn, cbn_sT, dd, 8192, 512);
    k_spectral<<<256, 512, 0, stream>>>(bbn_h, s, dd, cbn_sT, hbuf);
    k_out<<<256, 512, 0, stream>>>(hbuf, Wt, b, out);
}